// Round 3
// baseline (584.182 us; speedup 1.0000x reference)
//
#include <hip/hip_runtime.h>

#define NV 400000
#define KOFF 27
#define CD 64
#define DD 128
#define HH 128
#define WW 128
#define TABN (2*DD*HH*WW)
#define EPSV 1e-5f

typedef _Float16 f16;
typedef _Float16 f16x8 __attribute__((ext_vector_type(8)));
typedef float f32x16 __attribute__((ext_vector_type(16)));

// ---- workspace layout (bytes) ----
#define OFF_NBR   0ull
#define OFF_X1    43200000ull
#define OFF_X2    94400000ull
#define OFF_TAB   94400000ull     // table dead before x2 written
#define OFF_W2T   145600000ull
#define OFF_W3T   145821184ull
#define OFF_ZERO  146042368ull

#define GLDS16(gp, lp) __builtin_amdgcn_global_load_lds( \
    (__attribute__((address_space(1))) void*)(gp), \
    (__attribute__((address_space(3))) void*)(lp), 16, 0, 0)

// ---- init: table=-1; weights -> f16 chunk-major wTg[k][cin/8][cout][cin&7]; zero row
__global__ void k_init(const float* __restrict__ w2, const float* __restrict__ w3,
                       int* __restrict__ tab, f16* __restrict__ w2t,
                       f16* __restrict__ w3t, f16* __restrict__ zrow) {
    int t = blockIdx.x * 256 + threadIdx.x;           // grid: 4096*256
    int4* tv = (int4*)tab;
    if (t < TABN / 4) tv[t] = make_int4(-1, -1, -1, -1);
    if (t < KOFF * CD * CD) {
        int k = t >> 12, r = t & 4095, c = r >> 6, ci = r & 63;
        // dst slot: k*4096 + (ci>>3)*512 + c*8 + (ci&7)
        int d = (k << 12) + ((ci >> 3) << 9) + (c << 3) + (ci & 7);
        w2t[d] = (f16)w2[(k << 12) + (ci << 6) + c];
        w3t[d] = (f16)w3[(k << 12) + (ci << 6) + c];
    }
    if (t < CD) zrow[t] = (f16)0.f;
}

__global__ void k_scatter(const int4* __restrict__ coords, int* __restrict__ tab) {
    int i = blockIdx.x * 256 + threadIdx.x;
    if (i >= NV) return;
    int4 c = coords[i];  // (b,z,y,x)
    int flat = ((c.x * DD + c.y) * HH + c.z) * WW + c.w;
    tab[flat] = i;
}

__global__ void k_nbr(const int4* __restrict__ coords, const int* __restrict__ tab,
                      int* __restrict__ nbr) {
    int i = blockIdx.x * 256 + threadIdx.x;
    if (i >= NV) return;
    int4 c = coords[i];
    int k = 0;
    #pragma unroll
    for (int dz = -1; dz <= 1; dz++)
    #pragma unroll
    for (int dy = -1; dy <= 1; dy++)
    #pragma unroll
    for (int dx = -1; dx <= 1; dx++) {
        int z = c.y + dz, y = c.z + dy, x = c.w + dx;
        int idx = -1;
        if (z >= 0 && z < DD && y >= 0 && y < HH && x >= 0 && x < WW)
            idx = tab[((c.x * DD + z) * HH + y) * WW + x];
        nbr[k * NV + i] = idx;
        k++;
    }
}

// ---- layer 1: one thread per voxel, acc[64] in VGPRs, scalar weights ----
__global__ __launch_bounds__(256) void k_layer1(
        const float* __restrict__ feats, const int* __restrict__ nbr,
        const float* __restrict__ w1, const float* __restrict__ b1,
        const float* __restrict__ g1, const float* __restrict__ be1,
        const float* __restrict__ m1, const float* __restrict__ v1,
        f16* __restrict__ x1) {
    int i = blockIdx.x * 256 + threadIdx.x;
    bool act = (i < NV);
    int ii = act ? i : 0;

    float acc[CD];
    #pragma unroll
    for (int c = 0; c < CD; c++) acc[c] = 0.f;

    #pragma unroll
    for (int k = 0; k < KOFF; k++) {
        int idx = act ? nbr[k * NV + ii] : -1;
        float fk = (idx >= 0) ? feats[idx] : 0.f;
        #pragma unroll
        for (int c = 0; c < CD; c++)
            acc[c] = fmaf(fk, w1[k * CD + c], acc[c]);
    }
    if (!act) return;

    #pragma unroll
    for (int c0 = 0; c0 < CD; c0 += 8) {
        f16x8 o;
        #pragma unroll
        for (int j = 0; j < 8; j++) {
            int c = c0 + j;
            float sc = g1[c] * rsqrtf(v1[c] + EPSV);
            float y = (acc[c] - m1[c] + b1[c]) * sc + be1[c];
            o[j] = (f16)fmaxf(y, 0.f);
        }
        *(f16x8*)(x1 + (size_t)i * CD + c0) = o;
    }
}

// ---- conv v3: 3-stage software pipeline.
// A-frags gathered per-lane from global into VGPRs one iter ahead;
// B tile (8KB, chunk-major [c][n][16B]) double-buffered in LDS, staged one iter
// ahead; nbr indices loaded two iters ahead. One barrier per k; the MFMA phase
// of iter k covers the latency of all iter-k+1 loads.
template <bool OUTF32>
__global__ __launch_bounds__(256, 3) void k_conv(
        const f16* __restrict__ xin, const f16* __restrict__ wT,
        const int* __restrict__ nbr, const f16* __restrict__ zrow,
        const float* __restrict__ bb, const float* __restrict__ gg,
        const float* __restrict__ bee, const float* __restrict__ mm,
        const float* __restrict__ vv, void* __restrict__ outp) {
    __shared__ __align__(16) unsigned char sB[2][8192];

    const int tid = threadIdx.x;
    const int lane = tid & 63;
    const int wv = tid >> 6;
    const int g = lane >> 5;     // k-group within MFMA (0/1)
    const int ml = lane & 31;
    const long vbase = (long)blockIdx.x * 256;

    f32x16 acc[2][2];
    #pragma unroll
    for (int a = 0; a < 2; a++)
        #pragma unroll
        for (int b = 0; b < 2; b++) acc[a][b] = (f32x16)(0.f);

    const long row0 = vbase + wv * 64 + ml;          // vt=0 row
    const long row1 = row0 + 32;                     // vt=1 row
    const bool ok0 = (row0 < NV), ok1 = (row1 < NV);

    // stage B(k) -> buf[k&1]; linear LDS dest (wave-uniform base + lane*16)
    auto stageB = [&](int k) {
        #pragma unroll
        for (int it = 0; it < 2; it++) {
            int s = it * 256 + tid;
            const char* gp = (const char*)wT + ((size_t)k * 8192 + s * 16);
            char* lp = (char*)sB[k & 1] + it * 4096 + wv * 1024;
            GLDS16(gp, lp);
        }
    };
    // gather A(k) fragments using preloaded indices
    auto gatherA = [&](int i0, int i1, f16x8 dst[2][4]) {
        const char* a0 = (i0 >= 0) ? (const char*)xin + (size_t)i0 * 128
                                   : (const char*)zrow;
        const char* a1 = (i1 >= 0) ? (const char*)xin + (size_t)i1 * 128
                                   : (const char*)zrow;
        a0 += g * 16; a1 += g * 16;
        #pragma unroll
        for (int ks = 0; ks < 4; ks++) {
            dst[0][ks] = *(const f16x8*)(a0 + ks * 32);
            dst[1][ks] = *(const f16x8*)(a1 + ks * 32);
        }
    };

    f16x8 afrC[2][4], afrN[2][4];
    int idxN0, idxN1;

    // prologue: B(0); A(0); idx(1)
    stageB(0);
    {
        int i0 = ok0 ? nbr[row0] : -1;
        int i1 = ok1 ? nbr[row1] : -1;
        gatherA(i0, i1, afrC);
    }
    idxN0 = ok0 ? nbr[(size_t)1 * NV + row0] : -1;
    idxN1 = ok1 ? nbr[(size_t)1 * NV + row1] : -1;

    #pragma unroll 1
    for (int k = 0; k < KOFF; k++) {
        __syncthreads();  // B(k) staged+visible; prior reads of buf[(k+1)&1] done
        if (k + 1 < KOFF) {
            stageB(k + 1);
            gatherA(idxN0, idxN1, afrN);
        }
        if (k + 2 < KOFF) {
            idxN0 = ok0 ? nbr[(size_t)(k + 2) * NV + row0] : -1;
            idxN1 = ok1 ? nbr[(size_t)(k + 2) * NV + row1] : -1;
        }
        const unsigned char* bbuf = sB[k & 1];
        #pragma unroll
        for (int ks = 0; ks < 4; ks++) {
            int c = ks * 2 + g;
            f16x8 bfr[2];
            #pragma unroll
            for (int nt = 0; nt < 2; nt++) {
                int n = nt * 32 + ml;
                bfr[nt] = *(const f16x8*)(bbuf + (c * 64 + n) * 16);  // lane-linear
            }
            #pragma unroll
            for (int vt = 0; vt < 2; vt++)
                #pragma unroll
                for (int nt = 0; nt < 2; nt++)
                    acc[vt][nt] = __builtin_amdgcn_mfma_f32_32x32x16_f16(
                        afrC[vt][ks], bfr[nt], acc[vt][nt], 0, 0, 0);
        }
        #pragma unroll
        for (int vt = 0; vt < 2; vt++)
            #pragma unroll
            for (int ks = 0; ks < 4; ks++)
                afrC[vt][ks] = afrN[vt][ks];
    }

    // epilogue: BN+ReLU, store. C/D: col=lane&31, row=(r&3)+8*(r>>2)+4*(lane>>5)
    const long gib = vbase + wv * 64;
    #pragma unroll
    for (int nt = 0; nt < 2; nt++) {
        int cn = nt * 32 + ml;
        float sc = gg[cn] * rsqrtf(vv[cn] + EPSV);
        float sh = (bb[cn] - mm[cn]) * sc + bee[cn];
        #pragma unroll
        for (int vt = 0; vt < 2; vt++) {
            #pragma unroll
            for (int r = 0; r < 16; r++) {
                int row = (r & 3) + 8 * (r >> 2) + 4 * g;
                long gi = gib + vt * 32 + row;
                if (gi < NV) {
                    float y = fmaxf(acc[vt][nt][r] * sc + sh, 0.f);
                    if (OUTF32) ((float*)outp)[gi * 64 + cn] = y;
                    else        ((f16*)outp)[gi * 64 + cn] = (f16)y;
                }
            }
        }
    }
}

extern "C" void kernel_launch(void* const* d_in, const int* in_sizes, int n_in,
                              void* d_out, int out_size, void* d_ws, size_t ws_size,
                              hipStream_t stream) {
    (void)in_sizes; (void)n_in; (void)out_size; (void)ws_size;
    const float* feats = (const float*)d_in[0];
    const int4* coords = (const int4*)d_in[1];
    const float* w1 = (const float*)d_in[2];
    const float* b1 = (const float*)d_in[3];
    const float* g1 = (const float*)d_in[4];
    const float* be1 = (const float*)d_in[5];
    const float* m1 = (const float*)d_in[6];
    const float* v1 = (const float*)d_in[7];
    const float* w2 = (const float*)d_in[8];
    const float* b2 = (const float*)d_in[9];
    const float* g2 = (const float*)d_in[10];
    const float* be2 = (const float*)d_in[11];
    const float* m2 = (const float*)d_in[12];
    const float* v2 = (const float*)d_in[13];
    const float* w3 = (const float*)d_in[14];
    const float* b3 = (const float*)d_in[15];
    const float* g3 = (const float*)d_in[16];
    const float* be3 = (const float*)d_in[17];
    const float* m3 = (const float*)d_in[18];
    const float* v3 = (const float*)d_in[19];

    char* ws = (char*)d_ws;
    int* nbr  = (int*)(ws + OFF_NBR);
    f16* x1   = (f16*)(ws + OFF_X1);
    f16* x2   = (f16*)(ws + OFF_X2);
    int* tab  = (int*)(ws + OFF_TAB);
    f16* w2t  = (f16*)(ws + OFF_W2T);
    f16* w3t  = (f16*)(ws + OFF_W3T);
    f16* zrow = (f16*)(ws + OFF_ZERO);

    k_init<<<4096, 256, 0, stream>>>(w2, w3, tab, w2t, w3t, zrow);
    k_scatter<<<(NV + 255) / 256, 256, 0, stream>>>(coords, tab);
    k_nbr<<<(NV + 255) / 256, 256, 0, stream>>>(coords, tab, nbr);
    k_layer1<<<(NV + 255) / 256, 256, 0, stream>>>(feats, nbr, w1, b1, g1, be1, m1, v1, x1);
    const int convgrid = (NV + 255) / 256;  // 1563
    k_conv<false><<<convgrid, 256, 0, stream>>>(x1, w2t, nbr, zrow, b2, g2, be2, m2, v2, (void*)x2);
    k_conv<true><<<convgrid, 256, 0, stream>>>(x2, w3t, nbr, zrow, b3, g3, be3, m3, v3, d_out);
}

// Round 4
// 537.566 us; speedup vs baseline: 1.0867x; 1.0867x over previous
//
#include <hip/hip_runtime.h>

#define NV 400000
#define KOFF 27
#define CD 64
#define DD 128
#define HH 128
#define WW 128
#define TABN (2*DD*HH*WW)
#define EPSV 1e-5f

typedef _Float16 f16;
typedef _Float16 f16x8 __attribute__((ext_vector_type(8)));
typedef float f32x16 __attribute__((ext_vector_type(16)));

// ---- workspace layout (bytes) ----
#define OFF_NBR   0ull
#define OFF_X1    43200000ull
#define OFF_X2    94400000ull
#define OFF_TAB   94400000ull     // table dead before x2 written
#define OFF_W2T   145600000ull
#define OFF_W3T   145821184ull
#define OFF_ZERO  146042368ull

#define GLDS16(gp, lp) __builtin_amdgcn_global_load_lds( \
    (__attribute__((address_space(1))) void*)(gp), \
    (__attribute__((address_space(3))) void*)(lp), 16, 0, 0)

// ---- init: table=-1; weights -> f16 chunk-major wTg[k][cin/8][cout][cin&7]; zero row
__global__ void k_init(const float* __restrict__ w2, const float* __restrict__ w3,
                       int* __restrict__ tab, f16* __restrict__ w2t,
                       f16* __restrict__ w3t, f16* __restrict__ zrow) {
    int t = blockIdx.x * 256 + threadIdx.x;           // grid: 4096*256
    int4* tv = (int4*)tab;
    if (t < TABN / 4) tv[t] = make_int4(-1, -1, -1, -1);
    if (t < KOFF * CD * CD) {
        int k = t >> 12, r = t & 4095, c = r >> 6, ci = r & 63;
        int d = (k << 12) + ((ci >> 3) << 9) + (c << 3) + (ci & 7);
        w2t[d] = (f16)w2[(k << 12) + (ci << 6) + c];
        w3t[d] = (f16)w3[(k << 12) + (ci << 6) + c];
    }
    if (t < CD) zrow[t] = (f16)0.f;
}

__global__ void k_scatter(const int4* __restrict__ coords, int* __restrict__ tab) {
    int i = blockIdx.x * 256 + threadIdx.x;
    if (i >= NV) return;
    int4 c = coords[i];  // (b,z,y,x)
    int flat = ((c.x * DD + c.y) * HH + c.z) * WW + c.w;
    tab[flat] = i;
}

__global__ void k_nbr(const int4* __restrict__ coords, const int* __restrict__ tab,
                      int* __restrict__ nbr) {
    int i = blockIdx.x * 256 + threadIdx.x;
    if (i >= NV) return;
    int4 c = coords[i];
    int k = 0;
    #pragma unroll
    for (int dz = -1; dz <= 1; dz++)
    #pragma unroll
    for (int dy = -1; dy <= 1; dy++)
    #pragma unroll
    for (int dx = -1; dx <= 1; dx++) {     // dx fastest: x-1,x,x+1 share an L1 line
        int z = c.y + dz, y = c.z + dy, x = c.w + dx;
        int idx = -1;
        if (z >= 0 && z < DD && y >= 0 && y < HH && x >= 0 && x < WW)
            idx = tab[((c.x * DD + z) * HH + y) * WW + x];
        nbr[k * NV + i] = idx;
        k++;
    }
}

// ---- layer 1: one thread per voxel, acc[64] in VGPRs, scalar weights ----
__global__ __launch_bounds__(256) void k_layer1(
        const float* __restrict__ feats, const int* __restrict__ nbr,
        const float* __restrict__ w1, const float* __restrict__ b1,
        const float* __restrict__ g1, const float* __restrict__ be1,
        const float* __restrict__ m1, const float* __restrict__ v1,
        f16* __restrict__ x1) {
    int i = blockIdx.x * 256 + threadIdx.x;
    bool act = (i < NV);
    int ii = act ? i : 0;

    float acc[CD];
    #pragma unroll
    for (int c = 0; c < CD; c++) acc[c] = 0.f;

    #pragma unroll
    for (int k = 0; k < KOFF; k++) {
        int idx = act ? nbr[k * NV + ii] : -1;
        float fk = (idx >= 0) ? feats[idx] : 0.f;
        #pragma unroll
        for (int c = 0; c < CD; c++)
            acc[c] = fmaf(fk, w1[k * CD + c], acc[c]);
    }
    if (!act) return;

    #pragma unroll
    for (int c0 = 0; c0 < CD; c0 += 8) {
        f16x8 o;
        #pragma unroll
        for (int j = 0; j < 8; j++) {
            int c = c0 + j;
            float sc = g1[c] * rsqrtf(v1[c] + EPSV);
            float y = (acc[c] - m1[c] + b1[c]) * sc + be1[c];
            o[j] = (f16)fmaxf(y, 0.f);
        }
        *(f16x8*)(x1 + (size_t)i * CD + c0) = o;
    }
}

// ---- conv v4: TA-efficient gather-implicit-GEMM.
// Block = 128 threads (2 waves) x 128 voxels; cout split 2x32 between waves.
// A(k): 128 rows x 128B staged to LDS via global_load_lds with 8 contiguous
//   lanes per row (8 lines/instr), XOR chunk swizzle for conflict-free ds_read.
//   Double-buffered; staged one iter ahead (covered by MFMA phase).
// B(k): per-lane 16B frags straight from global (L1-hot), prefetched to VGPRs
//   one iter ahead. nbr indices prefetched two iters ahead.
// Epilogue: BN+ReLU -> LDS transpose -> vectorized dwordx4 stores.
template <bool OUTF32>
__global__ __launch_bounds__(128, 3) void k_conv(
        const f16* __restrict__ xin, const f16* __restrict__ wT,
        const int* __restrict__ nbr, const f16* __restrict__ zrow,
        const float* __restrict__ bb, const float* __restrict__ gg,
        const float* __restrict__ bee, const float* __restrict__ mm,
        const float* __restrict__ vv, void* __restrict__ outp) {
    __shared__ __align__(16) unsigned char sA[2][16384];   // 32 KB

    const int tid = threadIdx.x;
    const int lane = tid & 63;
    const int wv = tid >> 6;          // 0/1: cout half
    const int g = (lane >> 5) & 1;    // MFMA k-group
    const int ml = lane & 31;
    const long vbase = (long)blockIdx.x * 128;   // exact: 3125*128 = 400000

    f32x16 acc[4];
    #pragma unroll
    for (int vt = 0; vt < 4; vt++) acc[vt] = (f32x16)(0.f);

    // thread's staging row (8 slots it=0..7): row = it*16 + (tid>>3), chunk cX fixed
    const int rsub = tid >> 3;
    const int cX = (tid & 7) ^ (rsub & 7);      // global chunk for this thread's slots

    // stage A(k) -> buf: slot s = it*128+tid, lds addr s*16 (wave-uniform base+lane*16)
    auto stageA = [&](const int* idxv, unsigned char* buf) {
        #pragma unroll
        for (int it = 0; it < 8; it++) {
            int idx = idxv[it];
            const char* gp = (idx >= 0)
                ? (const char*)xin + ((size_t)idx * 128 + cX * 16)
                : (const char*)zrow + cX * 16;
            char* lp = (char*)buf + it * 2048 + wv * 1024;
            GLDS16(gp, lp);
        }
    };
    auto loadIdx = [&](int k, int* idxv) {
        #pragma unroll
        for (int it = 0; it < 8; it++)
            idxv[it] = nbr[(size_t)k * NV + vbase + it * 16 + rsub];
    };
    // B frag addresses: f16 offset = k*4096 + c*512 + cout*8, cout = wv*32+ml, c=ks*2+g
    auto loadB = [&](int k, f16x8* bfr) {
        #pragma unroll
        for (int ks = 0; ks < 4; ks++)
            bfr[ks] = *(const f16x8*)(wT + (size_t)k * 4096
                                      + (ks * 2 + g) * 512 + (wv * 32 + ml) * 8);
    };

    int idxC[8];
    f16x8 bfrC[4], bfrN[4];

    // prologue: A(0), idx(1), B(0)
    loadIdx(0, idxC);
    stageA(idxC, sA[0]);
    loadIdx(1, idxC);
    loadB(0, bfrC);

    #pragma unroll 1
    for (int k = 0; k < KOFF; k++) {
        __syncthreads();   // A(k) staged+visible; prior reads of buf[(k+1)&1] done
        if (k + 1 < KOFF) {
            stageA(idxC, sA[(k + 1) & 1]);
            if (k + 2 < KOFF) loadIdx(k + 2, idxC);
            loadB(k + 1, bfrN);
        }
        const unsigned char* buf = sA[k & 1];
        #pragma unroll
        for (int ks = 0; ks < 4; ks++) {
            int pos = (ks * 2 + g) ^ (ml & 7);   // XOR swizzle
            f16x8 a[4];
            #pragma unroll
            for (int vt = 0; vt < 4; vt++)
                a[vt] = *(const f16x8*)(buf + (vt * 32 + ml) * 128 + pos * 16);
            #pragma unroll
            for (int vt = 0; vt < 4; vt++)
                acc[vt] = __builtin_amdgcn_mfma_f32_32x32x16_f16(
                    a[vt], bfrC[ks], acc[vt], 0, 0, 0);
        }
        if (k + 1 < KOFF) {
            #pragma unroll
            for (int ks = 0; ks < 4; ks++) bfrC[ks] = bfrN[ks];
        }
    }

    // epilogue: BN+ReLU -> LDS (row-major) -> vectorized global stores
    const int cn = wv * 32 + ml;
    float sc = gg[cn] * rsqrtf(vv[cn] + EPSV);
    float sh = (bb[cn] - mm[cn]) * sc + bee[cn];
    unsigned char* sAll = (unsigned char*)sA;    // 32 KB contiguous
    __syncthreads();                             // main-loop ds_reads done
    #pragma unroll
    for (int vt = 0; vt < 4; vt++) {
        #pragma unroll
        for (int r = 0; r < 16; r++) {
            int row = vt * 32 + (r & 3) + 8 * (r >> 2) + 4 * g;
            float y = fmaxf(acc[vt][r] * sc + sh, 0.f);
            if (OUTF32) *(float*)(sAll + row * 256 + cn * 4) = y;
            else        *(f16*)(sAll + row * 128 + cn * 2) = (f16)y;
        }
    }
    __syncthreads();
    if (OUTF32) {
        char* gb = (char*)outp + vbase * 256;    // 128 rows x 256B = 32 KB
        #pragma unroll
        for (int it = 0; it < 16; it++) {
            int s = it * 128 + tid;
            *(float4*)(gb + s * 16) = *(const float4*)(sAll + s * 16);
        }
    } else {
        char* gb = (char*)outp + vbase * 128;    // 128 rows x 128B = 16 KB
        #pragma unroll
        for (int it = 0; it < 8; it++) {
            int s = it * 128 + tid;
            *(float4*)(gb + s * 16) = *(const float4*)(sAll + s * 16);
        }
    }
}

extern "C" void kernel_launch(void* const* d_in, const int* in_sizes, int n_in,
                              void* d_out, int out_size, void* d_ws, size_t ws_size,
                              hipStream_t stream) {
    (void)in_sizes; (void)n_in; (void)out_size; (void)ws_size;
    const float* feats = (const float*)d_in[0];
    const int4* coords = (const int4*)d_in[1];
    const float* w1 = (const float*)d_in[2];
    const float* b1 = (const float*)d_in[3];
    const float* g1 = (const float*)d_in[4];
    const float* be1 = (const float*)d_in[5];
    const float* m1 = (const float*)d_in[6];
    const float* v1 = (const float*)d_in[7];
    const float* w2 = (const float*)d_in[8];
    const float* b2 = (const float*)d_in[9];
    const float* g2 = (const float*)d_in[10];
    const float* be2 = (const float*)d_in[11];
    const float* m2 = (const float*)d_in[12];
    const float* v2 = (const float*)d_in[13];
    const float* w3 = (const float*)d_in[14];
    const float* b3 = (const float*)d_in[15];
    const float* g3 = (const float*)d_in[16];
    const float* be3 = (const float*)d_in[17];
    const float* m3 = (const float*)d_in[18];
    const float* v3 = (const float*)d_in[19];

    char* ws = (char*)d_ws;
    int* nbr  = (int*)(ws + OFF_NBR);
    f16* x1   = (f16*)(ws + OFF_X1);
    f16* x2   = (f16*)(ws + OFF_X2);
    int* tab  = (int*)(ws + OFF_TAB);
    f16* w2t  = (f16*)(ws + OFF_W2T);
    f16* w3t  = (f16*)(ws + OFF_W3T);
    f16* zrow = (f16*)(ws + OFF_ZERO);

    k_init<<<4096, 256, 0, stream>>>(w2, w3, tab, w2t, w3t, zrow);
    k_scatter<<<(NV + 255) / 256, 256, 0, stream>>>(coords, tab);
    k_nbr<<<(NV + 255) / 256, 256, 0, stream>>>(coords, tab, nbr);
    k_layer1<<<(NV + 255) / 256, 256, 0, stream>>>(feats, nbr, w1, b1, g1, be1, m1, v1, x1);
    const int convgrid = NV / 128;  // 3125, exact
    k_conv<false><<<convgrid, 128, 0, stream>>>(x1, w2t, nbr, zrow, b2, g2, be2, m2, v2, (void*)x2);
    k_conv<true><<<convgrid, 128, 0, stream>>>(x2, w3t, nbr, zrow, b3, g3, be3, m3, v3, d_out);
}